// Round 1
// baseline (2925.914 us; speedup 1.0000x reference)
//
#include <hip/hip_runtime.h>

#define N_NODES 20000
#define N_EDGES 100000
#define IN_DIM  128
#define HID     64
#define LAT     32
#define EDIM    16
#define EPB     16   // edges per wave in the edge-message kernel

// ---------------------------------------------------------------------------
// Kernel A: h = relu(x @ lin_in_w + lin_in_b)      [N,128]@[128,64] -> [N,64]
// one thread per output element; x reads broadcast per 64-lane group,
// lin_in_w reads coalesced (w is 32 KB -> L1/L2 resident).
// ---------------------------------------------------------------------------
__global__ void k_lin_in(const float* __restrict__ x,
                         const float* __restrict__ w,
                         const float* __restrict__ b,
                         float* __restrict__ h) {
    int t = blockIdx.x * blockDim.x + threadIdx.x;   // t in [0, N*HID)
    int n = t >> 6;
    int o = t & 63;
    const float* xr = x + n * IN_DIM;
    float acc = b[o];
#pragma unroll 8
    for (int d = 0; d < IN_DIM; ++d)
        acc = fmaf(xr[d], w[d * HID + o], acc);
    h[t] = fmaxf(acc, 0.f);
}

// ---------------------------------------------------------------------------
// Kernel B: fused edge-MLP + message + scatter-add.
// For each edge e:
//   W_e[hh,o] = relu( sum_d ea[e,d]*kw[d, hh*64+o] + kb[hh*64+o] )
//   msg[e,o]  = sum_hh h[src[e],hh] * W_e[hh,o]
//   atomicAdd(num[dst[e],o], msg[e,o]);  atomicAdd(cnt[dst[e]], 1)
// One wave handles EPB=16 edges; lane = output channel o. Per hh the wave
// caches the 16x64 ker_w slice in VGPRs (16 coalesced loads) and reuses it
// across all 16 edges. ea / h_src are staged in LDS, read broadcast.
// ---------------------------------------------------------------------------
__global__ void k_edge_msg(const int* __restrict__ ei,   // [2,E]
                           const float* __restrict__ ea, // [E,16]
                           const float* __restrict__ h,  // [N,64]
                           const float* __restrict__ kw, // [16,4096]
                           const float* __restrict__ kb, // [4096]
                           float* __restrict__ num,      // [N,64]  (zeroed)
                           float* __restrict__ cnt) {    // [N]     (zeroed)
    __shared__ float s_ea[4][EPB][EDIM];
    __shared__ float s_hs[4][EPB][HID];

    const int wave = threadIdx.x >> 6;
    const int lane = threadIdx.x & 63;
    const int e0   = (blockIdx.x * 4 + wave) * EPB;

    // stage edge_attr for this wave's 16 edges (clamped for the tail wave)
    for (int i = lane; i < EPB * EDIM; i += 64) {
        int b = i >> 4;          // /EDIM
        int d = i & 15;
        int e = e0 + b; if (e >= N_EDGES) e = N_EDGES - 1;
        s_ea[wave][b][d] = ea[e * EDIM + d];
    }
    // stage h[src] for the 16 edges
#pragma unroll
    for (int b = 0; b < EPB; ++b) {
        int e = e0 + b; if (e >= N_EDGES) e = N_EDGES - 1;
        int src = ei[e];
        s_hs[wave][b][lane] = h[src * HID + lane];
    }
    __syncthreads();

    float msg[EPB];
#pragma unroll
    for (int b = 0; b < EPB; ++b) msg[b] = 0.f;

    for (int hh = 0; hh < HID; ++hh) {
        // cache ker_w[:, hh*64 + lane] (16 values) in registers — coalesced
        float kwr[EDIM];
#pragma unroll
        for (int d = 0; d < EDIM; ++d)
            kwr[d] = kw[d * (HID * HID) + hh * HID + lane];
        const float kbb = kb[hh * HID + lane];

#pragma unroll
        for (int b = 0; b < EPB; ++b) {
            float w = kbb;
#pragma unroll
            for (int d = 0; d < EDIM; ++d)
                w = fmaf(s_ea[wave][b][d], kwr[d], w);
            w = fmaxf(w, 0.f);
            msg[b] = fmaf(s_hs[wave][b][hh], w, msg[b]);
        }
    }

    // scatter
#pragma unroll
    for (int b = 0; b < EPB; ++b) {
        int e = e0 + b;
        if (e < N_EDGES) {
            int dst = ei[N_EDGES + e];
            atomicAdd(&num[dst * HID + lane], msg[b]);
            if (lane == 0) atomicAdd(&cnt[dst], 1.f);
        }
    }
}

// ---------------------------------------------------------------------------
// Kernel C: agg = num / max(cnt,1);  h2 = relu(h@root_w + agg + conv_b);
//           mu = h2@mu_w + mu_b;  lv = h2@lv_w + lv_b.
// One wave per node; lane o computes h2[o] -> LDS; then lanes 0..31 compute
// mu, lanes 32..63 compute logvar.
// ---------------------------------------------------------------------------
__global__ void k_out(const float* __restrict__ h,
                      const float* __restrict__ num,
                      const float* __restrict__ cnt,
                      const float* __restrict__ root_w,  // [64,64]
                      const float* __restrict__ conv_b,  // [64]
                      const float* __restrict__ mu_w,    // [64,32]
                      const float* __restrict__ mu_b,    // [32]
                      const float* __restrict__ lv_w,    // [64,32]
                      const float* __restrict__ lv_b,    // [32]
                      float* __restrict__ out) {         // [2*N*32]
    __shared__ float s_h2[4][HID];
    const int wave = threadIdx.x >> 6;
    const int lane = threadIdx.x & 63;
    const int n = blockIdx.x * 4 + wave;

    float acc = num[n * HID + lane] / fmaxf(cnt[n], 1.f) + conv_b[lane];
    const float* hr = h + n * HID;
#pragma unroll 8
    for (int k = 0; k < HID; ++k)
        acc = fmaf(hr[k], root_w[k * HID + lane], acc);
    acc = fmaxf(acc, 0.f);
    s_h2[wave][lane] = acc;
    __syncthreads();

    const float* wsel = (lane < 32) ? mu_w : lv_w;
    const float* bsel = (lane < 32) ? mu_b : lv_b;
    const int l = lane & 31;
    float o = bsel[l];
#pragma unroll 8
    for (int k = 0; k < HID; ++k)
        o = fmaf(s_h2[wave][k], wsel[k * LAT + l], o);
    const int base = (lane < 32) ? 0 : N_NODES * LAT;
    out[base + n * LAT + l] = o;
}

// ---------------------------------------------------------------------------
extern "C" void kernel_launch(void* const* d_in, const int* in_sizes, int n_in,
                              void* d_out, int out_size, void* d_ws, size_t ws_size,
                              hipStream_t stream) {
    const float* x      = (const float*)d_in[0];
    const int*   ei     = (const int*)  d_in[1];
    const float* ea     = (const float*)d_in[2];
    const float* lin_w  = (const float*)d_in[3];
    const float* lin_b  = (const float*)d_in[4];
    const float* kw     = (const float*)d_in[5];
    const float* kb     = (const float*)d_in[6];
    const float* root_w = (const float*)d_in[7];
    const float* conv_b = (const float*)d_in[8];
    const float* mu_w   = (const float*)d_in[9];
    const float* mu_b   = (const float*)d_in[10];
    const float* lv_w   = (const float*)d_in[11];
    const float* lv_b   = (const float*)d_in[12];
    float* out = (float*)d_out;

    float* h   = (float*)d_ws;                       // N*64
    float* num = h   + (size_t)N_NODES * HID;        // N*64
    float* cnt = num + (size_t)N_NODES * HID;        // N

    hipMemsetAsync(num, 0, (size_t)(N_NODES * HID + N_NODES) * sizeof(float),
                   stream);

    k_lin_in<<<(N_NODES * HID) / 256, 256, 0, stream>>>(x, lin_w, lin_b, h);

    const int nwaves  = (N_EDGES + EPB - 1) / EPB;   // 6250
    const int nblocks = (nwaves + 3) / 4;            // 1563
    k_edge_msg<<<nblocks, 256, 0, stream>>>(ei, ea, h, kw, kb, num, cnt);

    k_out<<<N_NODES / 4, 256, 0, stream>>>(h, num, cnt, root_w, conv_b,
                                           mu_w, mu_b, lv_w, lv_b, out);
}

// Round 2
// 850.564 us; speedup vs baseline: 3.4400x; 3.4400x over previous
//
#include <hip/hip_runtime.h>

#define N_NODES 20000
#define N_EDGES 100000
#define IN_DIM  128
#define HID     64
#define LAT     32
#define EDIM    16

// ---------------------------------------------------------------------------
// Prep: transpose kw [16][4096] -> kwT [4096][16] so that one output column's
// 16 weights are a contiguous 64 B row (wave-uniform scalar-load friendly).
// ---------------------------------------------------------------------------
__global__ __launch_bounds__(256) void k_prep(const float* __restrict__ kw,
                                              float* __restrict__ kwT) {
    int i = blockIdx.x * 256 + threadIdx.x;      // 0 .. 65535
    int c = i & 4095;
    int d = i >> 12;
    kwT[c * EDIM + d] = kw[d * (HID * HID) + c];
}

// ---------------------------------------------------------------------------
// Kernel A: h = relu(x @ lin_in_w + lin_in_b)      [N,128]@[128,64] -> [N,64]
// ---------------------------------------------------------------------------
__global__ __launch_bounds__(256) void k_lin_in(const float* __restrict__ x,
                                                const float* __restrict__ w,
                                                const float* __restrict__ b,
                                                float* __restrict__ h) {
    int t = blockIdx.x * blockDim.x + threadIdx.x;   // t in [0, N*HID)
    int n = t >> 6;
    int o = t & 63;
    const float* xr = x + n * IN_DIM;
    float acc = b[o];
#pragma unroll 8
    for (int d = 0; d < IN_DIM; ++d)
        acc = fmaf(xr[d], w[d * HID + o], acc);
    h[t] = fmaxf(acc, 0.f);
}

// ---------------------------------------------------------------------------
// Kernel B: fused edge-MLP + message + scatter-add.
// Lane = edge. ea[16] per-lane in VGPRs, msg[64] per-lane accumulator
// (statically indexed via full unroll). kwT/kb reads are wave-uniform ->
// scalar loads; the 256 KB kwT stream is shared by all waves (L2-resident),
// so HBM traffic collapses from 9.3 GB to ~0.1 GB.
//   c = hh*64 + oo:  W_e[c] = relu(kb[c] + sum_d ea[e,d]*kwT[c][d])
//   msg[e,oo] += h[src[e],hh] * W_e[c]
// ---------------------------------------------------------------------------
__global__ __launch_bounds__(256) void k_edge(const int* __restrict__ ei,
                                              const float* __restrict__ ea,
                                              const float* __restrict__ h,
                                              const float* __restrict__ kwT,
                                              const float* __restrict__ kb,
                                              float* __restrict__ num,
                                              float* __restrict__ cnt) {
    const int wid  = blockIdx.x * 4 + (threadIdx.x >> 6);
    const int lane = threadIdx.x & 63;
    int e = wid * 64 + lane;
    const bool valid = e < N_EDGES;
    if (!valid) e = N_EDGES - 1;
    const int src = ei[e];
    const int dst = ei[N_EDGES + e];

    float ear[EDIM];
    {
        const float4* p = (const float4*)(ea + (size_t)e * EDIM);
#pragma unroll
        for (int i = 0; i < 4; ++i) {
            float4 v = p[i];
            ear[4*i+0] = v.x; ear[4*i+1] = v.y;
            ear[4*i+2] = v.z; ear[4*i+3] = v.w;
        }
    }

    float msg[HID];
#pragma unroll
    for (int o = 0; o < HID; ++o) msg[o] = 0.f;

    const float* __restrict__ hrow = h + (size_t)src * HID;

    for (int hh = 0; hh < HID; ++hh) {
        const float hv = hrow[hh];                       // per-lane gather
        const float* __restrict__ kr  = kwT + (size_t)hh * HID * EDIM;
        const float* __restrict__ kbb = kb + hh * HID;   // wave-uniform
#pragma unroll
        for (int oo = 0; oo < HID; ++oo) {
            const float4* kp = (const float4*)(kr + oo * EDIM);  // uniform
            float4 k0 = kp[0], k1 = kp[1], k2 = kp[2], k3 = kp[3];
            float w = kbb[oo];
            w = fmaf(ear[0],  k0.x, w); w = fmaf(ear[1],  k0.y, w);
            w = fmaf(ear[2],  k0.z, w); w = fmaf(ear[3],  k0.w, w);
            w = fmaf(ear[4],  k1.x, w); w = fmaf(ear[5],  k1.y, w);
            w = fmaf(ear[6],  k1.z, w); w = fmaf(ear[7],  k1.w, w);
            w = fmaf(ear[8],  k2.x, w); w = fmaf(ear[9],  k2.y, w);
            w = fmaf(ear[10], k2.z, w); w = fmaf(ear[11], k2.w, w);
            w = fmaf(ear[12], k3.x, w); w = fmaf(ear[13], k3.y, w);
            w = fmaf(ear[14], k3.z, w); w = fmaf(ear[15], k3.w, w);
            w = fmaxf(w, 0.f);
            msg[oo] = fmaf(hv, w, msg[oo]);
        }
    }

    if (valid) {
        float* np_ = num + (size_t)dst * HID;
#pragma unroll
        for (int o = 0; o < HID; ++o) atomicAdd(np_ + o, msg[o]);
        atomicAdd(cnt + dst, 1.f);
    }
}

// ---------------------------------------------------------------------------
// Kernel C: agg = num / max(cnt,1);  h2 = relu(h@root_w + agg + conv_b);
//           mu = h2@mu_w + mu_b;  lv = h2@lv_w + lv_b.
// ---------------------------------------------------------------------------
__global__ __launch_bounds__(256) void k_out(const float* __restrict__ h,
                      const float* __restrict__ num,
                      const float* __restrict__ cnt,
                      const float* __restrict__ root_w,  // [64,64]
                      const float* __restrict__ conv_b,  // [64]
                      const float* __restrict__ mu_w,    // [64,32]
                      const float* __restrict__ mu_b,    // [32]
                      const float* __restrict__ lv_w,    // [64,32]
                      const float* __restrict__ lv_b,    // [32]
                      float* __restrict__ out) {         // [2*N*32]
    __shared__ float s_h2[4][HID];
    const int wave = threadIdx.x >> 6;
    const int lane = threadIdx.x & 63;
    const int n = blockIdx.x * 4 + wave;

    float acc = num[n * HID + lane] / fmaxf(cnt[n], 1.f) + conv_b[lane];
    const float* hr = h + n * HID;
#pragma unroll 8
    for (int k = 0; k < HID; ++k)
        acc = fmaf(hr[k], root_w[k * HID + lane], acc);
    acc = fmaxf(acc, 0.f);
    s_h2[wave][lane] = acc;
    __syncthreads();

    const float* wsel = (lane < 32) ? mu_w : lv_w;
    const float* bsel = (lane < 32) ? mu_b : lv_b;
    const int l = lane & 31;
    float o = bsel[l];
#pragma unroll 8
    for (int k = 0; k < HID; ++k)
        o = fmaf(s_h2[wave][k], wsel[k * LAT + l], o);
    const int base = (lane < 32) ? 0 : N_NODES * LAT;
    out[base + n * LAT + l] = o;
}

// ---------------------------------------------------------------------------
extern "C" void kernel_launch(void* const* d_in, const int* in_sizes, int n_in,
                              void* d_out, int out_size, void* d_ws, size_t ws_size,
                              hipStream_t stream) {
    const float* x      = (const float*)d_in[0];
    const int*   ei     = (const int*)  d_in[1];
    const float* ea     = (const float*)d_in[2];
    const float* lin_w  = (const float*)d_in[3];
    const float* lin_b  = (const float*)d_in[4];
    const float* kw     = (const float*)d_in[5];
    const float* kb     = (const float*)d_in[6];
    const float* root_w = (const float*)d_in[7];
    const float* conv_b = (const float*)d_in[8];
    const float* mu_w   = (const float*)d_in[9];
    const float* mu_b   = (const float*)d_in[10];
    const float* lv_w   = (const float*)d_in[11];
    const float* lv_b   = (const float*)d_in[12];
    float* out = (float*)d_out;

    float* h   = (float*)d_ws;                       // N*64
    float* num = h   + (size_t)N_NODES * HID;        // N*64
    float* cnt = num + (size_t)N_NODES * HID;        // N
    float* kwT = cnt + (size_t)N_NODES;              // 4096*16

    hipMemsetAsync(num, 0, (size_t)(N_NODES * HID + N_NODES) * sizeof(float),
                   stream);

    k_prep<<<(HID * HID * EDIM) / 256, 256, 0, stream>>>(kw, kwT);
    k_lin_in<<<(N_NODES * HID) / 256, 256, 0, stream>>>(x, lin_w, lin_b, h);

    const int nwaves  = (N_EDGES + 63) / 64;         // 1563
    const int nblocks = (nwaves + 3) / 4;            // 391
    k_edge<<<nblocks, 256, 0, stream>>>(ei, ea, h, kwT, kb, num, cnt);

    k_out<<<N_NODES / 4, 256, 0, stream>>>(h, num, cnt, root_w, conv_b,
                                           mu_w, mu_b, lv_w, lv_b, out);
}

// Round 3
// 172.429 us; speedup vs baseline: 16.9688x; 4.9328x over previous
//
#include <hip/hip_runtime.h>
#include <hip/hip_bf16.h>

#define N_NODES 20000
#define N_EDGES 100000
#define IN_DIM  128
#define HID     64
#define LAT     32
#define EDIM    16

typedef __attribute__((ext_vector_type(8))) short bf16x8;
typedef __attribute__((ext_vector_type(4))) float f32x4;

// ---------------------------------------------------------------------------
// Prep 1: kwT_bf[c][d] = bf16(kw[d][c])   (4096 x 16, 128 KB, L2-resident)
// ---------------------------------------------------------------------------
__global__ __launch_bounds__(256) void k_prep_kw(const float* __restrict__ kw,
                                                 __hip_bfloat16* __restrict__ kwT) {
    int i = blockIdx.x * 256 + threadIdx.x;      // 0 .. 65535
    int c = i & 4095;
    int d = i >> 12;
    kwT[c * EDIM + d] = __float2bfloat16(kw[d * (HID * HID) + c]);
}

// Prep 2: ea_bf[e][d] = bf16(ea[e][d])
__global__ __launch_bounds__(256) void k_prep_ea(const float* __restrict__ ea,
                                                 __hip_bfloat16* __restrict__ eab) {
    int i = blockIdx.x * 256 + threadIdx.x;      // 0 .. E*16-1
    eab[i] = __float2bfloat16(ea[i]);
}

// ---------------------------------------------------------------------------
// Kernel A: h = relu(x @ lin_in_w + lin_in_b)
// ---------------------------------------------------------------------------
__global__ __launch_bounds__(256) void k_lin_in(const float* __restrict__ x,
                                                const float* __restrict__ w,
                                                const float* __restrict__ b,
                                                float* __restrict__ h) {
    int t = blockIdx.x * blockDim.x + threadIdx.x;
    int n = t >> 6;
    int o = t & 63;
    const float* xr = x + n * IN_DIM;
    float acc = b[o];
#pragma unroll 8
    for (int d = 0; d < IN_DIM; ++d)
        acc = fmaf(xr[d], w[d * HID + o], acc);
    h[t] = fmaxf(acc, 0.f);
}

// ---------------------------------------------------------------------------
// Kernel B (MFMA): fused edge-MLP + message + scatter-add.
// Block = one 16-edge group; wave q owns output cols [q*16, q*16+16).
// Per hh: one mfma_f32_16x16x32_bf16 computes the 16x16 W_e tile
//   A (16x32): rows = edges, k<16 = edge_attr (bf16), k>=16 = 0
//   B (32x16): cols = oo,    k<16 = kwT rows (bf16),  k>=16 = 0
//   C in      = bias kb[c] broadcast over rows
// Fragment layout (gfx950): A/B lane l -> row/col = l&15, k = (l>>4)*8+i
// (lanes >=32 hold k=16..31 -> zeroed). D: col = l&15, row = (l>>4)*4+j.
// Epilogue: relu, then msg[j] += W[j] * h_src[row][hh] (LDS broadcast).
// ---------------------------------------------------------------------------
__global__ __launch_bounds__(256) void k_edge(const int* __restrict__ ei,
                                              const __hip_bfloat16* __restrict__ eab,
                                              const float* __restrict__ h,
                                              const __hip_bfloat16* __restrict__ kwT,
                                              const float* __restrict__ kb,
                                              float* __restrict__ num,
                                              float* __restrict__ cnt) {
    __shared__ float s_h[16][65];     // padded: j-read hits 4 distinct banks
    __shared__ int   s_dst[16];

    const int e0   = blockIdx.x * 16;
    const int tid  = threadIdx.x;
    const int q    = tid >> 6;        // wave id = oo quarter
    const int lane = tid & 63;

    // stage h[src] (16 x 64) and dst indices
    for (int i = tid; i < 16 * HID; i += 256) {
        int r = i >> 6, c = i & 63;
        int src = ei[e0 + r];
        s_h[r][c] = h[(size_t)src * HID + c];
    }
    if (tid < 16) s_dst[tid] = ei[N_EDGES + e0 + tid];
    __syncthreads();

    const int col = lane & 15;
    const int grp = lane >> 4;        // 0..3

    // A fragment: loop-invariant (edge_attr of this group's 16 edges)
    bf16x8 a_frag = {};
    if (lane < 32)
        a_frag = *(const bf16x8*)(eab + (size_t)(e0 + col) * EDIM + (grp & 1) * 8);

    f32x4 msg = {0.f, 0.f, 0.f, 0.f};

    // B base: kwT row (hh*64 + q*16 + col), halves split across lane groups
    const __hip_bfloat16* bptr = kwT + (size_t)(q * 16 + col) * EDIM + (grp & 1) * 8;
    const float* kbp = kb + q * 16 + col;

    for (int hh = 0; hh < HID; ++hh) {
        bf16x8 b_frag = {};
        if (lane < 32)
            b_frag = *(const bf16x8*)(bptr + (size_t)hh * (HID * EDIM));
        const float kbv = kbp[hh * HID];
        f32x4 cin = {kbv, kbv, kbv, kbv};
        f32x4 w = __builtin_amdgcn_mfma_f32_16x16x32_bf16(a_frag, b_frag, cin,
                                                          0, 0, 0);
#pragma unroll
        for (int j = 0; j < 4; ++j) {
            float wv = fmaxf(w[j], 0.f);
            msg[j] = fmaf(wv, s_h[grp * 4 + j][hh], msg[j]);
        }
    }

    // scatter: D element (row = grp*4+j -> edge, col -> oo = q*16+col)
#pragma unroll
    for (int j = 0; j < 4; ++j) {
        int dst = s_dst[grp * 4 + j];
        atomicAdd(num + (size_t)dst * HID + q * 16 + col, msg[j]);
    }
    if (tid < 16) atomicAdd(cnt + s_dst[tid], 1.f);
}

// ---------------------------------------------------------------------------
// Kernel C: agg = num / max(cnt,1);  h2 = relu(h@root_w + agg + conv_b);
//           mu = h2@mu_w + mu_b;  lv = h2@lv_w + lv_b.
// ---------------------------------------------------------------------------
__global__ __launch_bounds__(256) void k_out(const float* __restrict__ h,
                      const float* __restrict__ num,
                      const float* __restrict__ cnt,
                      const float* __restrict__ root_w,
                      const float* __restrict__ conv_b,
                      const float* __restrict__ mu_w,
                      const float* __restrict__ mu_b,
                      const float* __restrict__ lv_w,
                      const float* __restrict__ lv_b,
                      float* __restrict__ out) {
    __shared__ float s_h2[4][HID];
    const int wave = threadIdx.x >> 6;
    const int lane = threadIdx.x & 63;
    const int n = blockIdx.x * 4 + wave;

    float acc = num[n * HID + lane] / fmaxf(cnt[n], 1.f) + conv_b[lane];
    const float* hr = h + n * HID;
#pragma unroll 8
    for (int k = 0; k < HID; ++k)
        acc = fmaf(hr[k], root_w[k * HID + lane], acc);
    acc = fmaxf(acc, 0.f);
    s_h2[wave][lane] = acc;
    __syncthreads();

    const float* wsel = (lane < 32) ? mu_w : lv_w;
    const float* bsel = (lane < 32) ? mu_b : lv_b;
    const int l = lane & 31;
    float o = bsel[l];
#pragma unroll 8
    for (int k = 0; k < HID; ++k)
        o = fmaf(s_h2[wave][k], wsel[k * LAT + l], o);
    const int base = (lane < 32) ? 0 : N_NODES * LAT;
    out[base + n * LAT + l] = o;
}

// ---------------------------------------------------------------------------
extern "C" void kernel_launch(void* const* d_in, const int* in_sizes, int n_in,
                              void* d_out, int out_size, void* d_ws, size_t ws_size,
                              hipStream_t stream) {
    const float* x      = (const float*)d_in[0];
    const int*   ei     = (const int*)  d_in[1];
    const float* ea     = (const float*)d_in[2];
    const float* lin_w  = (const float*)d_in[3];
    const float* lin_b  = (const float*)d_in[4];
    const float* kw     = (const float*)d_in[5];
    const float* kb     = (const float*)d_in[6];
    const float* root_w = (const float*)d_in[7];
    const float* conv_b = (const float*)d_in[8];
    const float* mu_w   = (const float*)d_in[9];
    const float* mu_b   = (const float*)d_in[10];
    const float* lv_w   = (const float*)d_in[11];
    const float* lv_b   = (const float*)d_in[12];
    float* out = (float*)d_out;

    float* h   = (float*)d_ws;                             // N*64 f32
    float* num = h   + (size_t)N_NODES * HID;              // N*64 f32
    float* cnt = num + (size_t)N_NODES * HID;              // N f32
    __hip_bfloat16* kwT = (__hip_bfloat16*)(cnt + N_NODES);        // 4096*16
    __hip_bfloat16* eab = kwT + (size_t)HID * HID * EDIM;          // E*16

    hipMemsetAsync(num, 0, (size_t)(N_NODES * HID + N_NODES) * sizeof(float),
                   stream);

    k_prep_kw<<<(HID * HID * EDIM) / 256, 256, 0, stream>>>(kw, kwT);
    k_prep_ea<<<(N_EDGES * EDIM) / 256, 256, 0, stream>>>(ea, eab);
    k_lin_in<<<(N_NODES * HID) / 256, 256, 0, stream>>>(x, lin_w, lin_b, h);

    k_edge<<<N_EDGES / 16, 256, 0, stream>>>(ei, eab, h, kwT, kb, num, cnt);

    k_out<<<N_NODES / 4, 256, 0, stream>>>(h, num, cnt, root_w, conv_b,
                                           mu_w, mu_b, lv_w, lv_b, out);
}

// Round 4
// 100.163 us; speedup vs baseline: 29.2115x; 1.7215x over previous
//
#include <hip/hip_runtime.h>
#include <hip/hip_bf16.h>

#define N_NODES 20000
#define N_EDGES 100000
#define IN_DIM  128
#define HID     64
#define LAT     32
#define EDIM    16

typedef __attribute__((ext_vector_type(8))) short bf16x8;
typedef __attribute__((ext_vector_type(4))) float f32x4;

__device__ __forceinline__ short f2bs(float f) {
    __hip_bfloat16 b = __float2bfloat16(f);
    short s;
    __builtin_memcpy(&s, &b, 2);
    return s;
}

// ---------------------------------------------------------------------------
// Fused prep: build all bf16 transposed weight tables in ws.
//   kwT  [4096][16] : kwT[c][d]  = kw[d][c]          (65536)
//   kbb8 [4096][8]  : kb[c] replicated 8x            (32768)
//   wT   [64][128]  : wT[o][d]   = lin_w[d][o]       (8192)
//   rootT[64][64]   : rootT[o][d]= root_w[d][o]      (4096)
//   mlvT [64][64]   : o<32 -> mu_w[k][o], else lv_w  (4096)
// total 114688 elements = 448 blocks x 256
// ---------------------------------------------------------------------------
__global__ __launch_bounds__(256) void k_prep(
        const float* __restrict__ kw,     const float* __restrict__ kb,
        const float* __restrict__ lin_w,  const float* __restrict__ root_w,
        const float* __restrict__ mu_w,   const float* __restrict__ lv_w,
        __hip_bfloat16* __restrict__ kwT, __hip_bfloat16* __restrict__ kbb8,
        __hip_bfloat16* __restrict__ wT,  __hip_bfloat16* __restrict__ rootT,
        __hip_bfloat16* __restrict__ mlvT) {
    int i = blockIdx.x * 256 + threadIdx.x;
    if (i < 65536) {
        int c = i & 4095, d = i >> 12;
        kwT[c * EDIM + d] = __float2bfloat16(kw[d * (HID * HID) + c]);
    } else if (i < 65536 + 32768) {
        int j = i - 65536;
        kbb8[j] = __float2bfloat16(kb[j >> 3]);
    } else if (i < 65536 + 32768 + 8192) {
        int j = i - (65536 + 32768);
        int o = j >> 7, d = j & 127;
        wT[j] = __float2bfloat16(lin_w[d * HID + o]);
    } else if (i < 65536 + 32768 + 8192 + 4096) {
        int j = i - (65536 + 32768 + 8192);
        int o = j >> 6, d = j & 63;
        rootT[j] = __float2bfloat16(root_w[d * HID + o]);
    } else {
        int j = i - (65536 + 32768 + 8192 + 4096);
        int o2 = j >> 6, k = j & 63;
        mlvT[j] = __float2bfloat16(o2 < 32 ? mu_w[k * LAT + o2]
                                           : lv_w[k * LAT + (o2 - 32)]);
    }
}

// ---------------------------------------------------------------------------
// Kernel A (MFMA): h = relu(x @ lin_in_w + lin_in_b)
// Block = 16 nodes, wave q = oo quarter. K=128 -> 4 MFMAs, full K used.
// A: row=lane&15 (node), k=(lane>>4)*8+i (+it*32), from x (f32->bf16 in-reg)
// B: col=lane&15 (oo),   k likewise, from wT (contiguous 16B)
// D: col=lane&15 (oo), row=(lane>>4)*4+j (node)
// ---------------------------------------------------------------------------
__global__ __launch_bounds__(256) void k_lin_mfma(
        const float* __restrict__ x, const __hip_bfloat16* __restrict__ wT,
        const float* __restrict__ lin_b, float* __restrict__ h) {
    const int n0   = blockIdx.x * 16;
    const int q    = threadIdx.x >> 6;
    const int lane = threadIdx.x & 63;
    const int col  = lane & 15, grp = lane >> 4;
    const int oo   = q * 16 + col;

    f32x4 acc = {0.f, 0.f, 0.f, 0.f};
    const float* xp = x + (size_t)(n0 + col) * IN_DIM + grp * 8;
    const __hip_bfloat16* bp = wT + (size_t)oo * IN_DIM + grp * 8;
#pragma unroll
    for (int it = 0; it < 4; ++it) {
        float4 xa = *(const float4*)(xp + it * 32);
        float4 xb = *(const float4*)(xp + it * 32 + 4);
        bf16x8 af;
        af[0] = f2bs(xa.x); af[1] = f2bs(xa.y); af[2] = f2bs(xa.z); af[3] = f2bs(xa.w);
        af[4] = f2bs(xb.x); af[5] = f2bs(xb.y); af[6] = f2bs(xb.z); af[7] = f2bs(xb.w);
        bf16x8 bfv = *(const bf16x8*)(bp + it * 32);
        acc = __builtin_amdgcn_mfma_f32_16x16x32_bf16(af, bfv, acc, 0, 0, 0);
    }
    const float bias = lin_b[oo];
#pragma unroll
    for (int j = 0; j < 4; ++j) {
        int row = grp * 4 + j;
        h[(size_t)(n0 + row) * HID + oo] = fmaxf(acc[j] + bias, 0.f);
    }
}

// ---------------------------------------------------------------------------
// Kernel B (MFMA): fused edge-MLP + message + scatter-add.
// Block = 16 edges, wave q = oo quarter. Per hh one 16x16x32 MFMA:
//   k<16  (grp0/1): A = edge_attr (bf16), B = kwT rows      -> ea @ kw
//   k=16  (grp2)  : A = 1.0,              B = kbb8 (bias)   -> + kb
//   k>16  (grp2/3): A = 0                                    (B don't-care)
// C = 0. Epilogue: relu, msg[j] += w[j] * s_hT[hh][grp*4+j] (1 ds_read_b128).
// b-address: single uniform base (kwT||kbb8), 32-bit element offset +=
// per-lane constant stride (1024 or 512). Scatter via atomics.
// ---------------------------------------------------------------------------
__global__ __launch_bounds__(256) void k_edge(
        const int* __restrict__ ei, const float* __restrict__ ea,
        const float* __restrict__ h, const __hip_bfloat16* __restrict__ kwT,
        float* __restrict__ num, float* __restrict__ cnt) {
    __shared__ float s_hT[HID][20];   // transposed h_src; 80B rows (16B mult)
    __shared__ int   s_dst[16];

    const int e0   = blockIdx.x * 16;
    const int tid  = threadIdx.x;
    const int q    = tid >> 6, lane = tid & 63;
    const int col  = lane & 15, grp = lane >> 4;

    // stage h[src]^T: wave-coalesced reads (one 256B row per 64 threads)
    for (int i = tid; i < 16 * HID; i += 256) {
        int r = i >> 6, c = i & 63;
        int src = ei[e0 + r];
        s_hT[c][r] = h[(size_t)src * HID + c];
    }
    if (tid < 16) s_dst[tid] = ei[N_EDGES + e0 + tid];
    __syncthreads();

    // A fragment (loop-invariant)
    bf16x8 af = {};
    if (grp < 2) {
        const float* ep = ea + (size_t)(e0 + col) * EDIM + grp * 8;
        float4 a0 = *(const float4*)ep;
        float4 a1 = *(const float4*)(ep + 4);
        af[0] = f2bs(a0.x); af[1] = f2bs(a0.y); af[2] = f2bs(a0.z); af[3] = f2bs(a0.w);
        af[4] = f2bs(a1.x); af[5] = f2bs(a1.y); af[6] = f2bs(a1.z); af[7] = f2bs(a1.w);
    } else if (grp == 2) {
        af[0] = (short)0x3F80;   // bf16(1.0) -> picks up bias row k=16
    }

    int off, stride;
    if (grp < 2) { off = (q * 16 + col) * EDIM + grp * 8; stride = 1024; }
    else         { off = 65536 + (q * 16 + col) * 8;      stride = 512;  }

    f32x4 msg = {0.f, 0.f, 0.f, 0.f};
    const f32x4 z = {0.f, 0.f, 0.f, 0.f};
#pragma unroll 8
    for (int hh = 0; hh < HID; ++hh) {
        bf16x8 bfv = *(const bf16x8*)(kwT + off);
        off += stride;
        f32x4 w = __builtin_amdgcn_mfma_f32_16x16x32_bf16(af, bfv, z, 0, 0, 0);
        float4 hv = *(const float4*)&s_hT[hh][grp * 4];
        msg[0] = fmaf(fmaxf(w[0], 0.f), hv.x, msg[0]);
        msg[1] = fmaf(fmaxf(w[1], 0.f), hv.y, msg[1]);
        msg[2] = fmaf(fmaxf(w[2], 0.f), hv.z, msg[2]);
        msg[3] = fmaf(fmaxf(w[3], 0.f), hv.w, msg[3]);
    }

#pragma unroll
    for (int j = 0; j < 4; ++j) {
        int dst = s_dst[grp * 4 + j];
        atomicAdd(num + (size_t)dst * HID + q * 16 + col, msg[j]);
    }
    if (tid < 16) atomicAdd(cnt + s_dst[tid], 1.f);
}

// ---------------------------------------------------------------------------
// Kernel C (MFMA): agg/root/heads fused. Block = 16 nodes.
// phase1: h2 = relu(h@root_w + num/max(cnt,1) + conv_b)  -> s_h2 (bf16, LDS)
// phase2: [mu|lv] = h2 @ [mu_w|lv_w] + [mu_b|lv_b]       -> out
// ---------------------------------------------------------------------------
__global__ __launch_bounds__(256) void k_out(
        const float* __restrict__ h, const float* __restrict__ num,
        const float* __restrict__ cnt,
        const __hip_bfloat16* __restrict__ rootT, const float* __restrict__ conv_b,
        const __hip_bfloat16* __restrict__ mlvT,  const float* __restrict__ mu_b,
        const float* __restrict__ lv_b, float* __restrict__ out) {
    __shared__ __align__(16) __hip_bfloat16 s_h2[16][72];  // 144B rows
    const int n0   = blockIdx.x * 16;
    const int q    = threadIdx.x >> 6;
    const int lane = threadIdx.x & 63;
    const int col  = lane & 15, grp = lane >> 4;
    const int oo   = q * 16 + col;

    // phase 1
    f32x4 acc = {0.f, 0.f, 0.f, 0.f};
    const float* hp = h + (size_t)(n0 + col) * HID + grp * 8;
    const __hip_bfloat16* bp = rootT + (size_t)oo * HID + grp * 8;
#pragma unroll
    for (int it = 0; it < 2; ++it) {
        float4 xa = *(const float4*)(hp + it * 32);
        float4 xb = *(const float4*)(hp + it * 32 + 4);
        bf16x8 af;
        af[0] = f2bs(xa.x); af[1] = f2bs(xa.y); af[2] = f2bs(xa.z); af[3] = f2bs(xa.w);
        af[4] = f2bs(xb.x); af[5] = f2bs(xb.y); af[6] = f2bs(xb.z); af[7] = f2bs(xb.w);
        bf16x8 bfv = *(const bf16x8*)(bp + it * 32);
        acc = __builtin_amdgcn_mfma_f32_16x16x32_bf16(af, bfv, acc, 0, 0, 0);
    }
    const float cb = conv_b[oo];
#pragma unroll
    for (int j = 0; j < 4; ++j) {
        int row = grp * 4 + j;
        int n = n0 + row;
        float agg = num[(size_t)n * HID + oo] / fmaxf(cnt[n], 1.f);
        s_h2[row][oo] = __float2bfloat16(fmaxf(acc[j] + agg + cb, 0.f));
    }
    __syncthreads();

    // phase 2
    f32x4 acc2 = {0.f, 0.f, 0.f, 0.f};
    const __hip_bfloat16* b2 = mlvT + (size_t)oo * HID + grp * 8;
#pragma unroll
    for (int it = 0; it < 2; ++it) {
        bf16x8 af = *(const bf16x8*)((const char*)&s_h2[col][0] + it * 64 + grp * 16);
        bf16x8 bfv = *(const bf16x8*)(b2 + it * 32);
        acc2 = __builtin_amdgcn_mfma_f32_16x16x32_bf16(af, bfv, acc2, 0, 0, 0);
    }
    const float bias = (oo < 32) ? mu_b[oo] : lv_b[oo - 32];
    float* obase = (oo < 32) ? (out + oo) : (out + (size_t)N_NODES * LAT + (oo - 32));
#pragma unroll
    for (int j = 0; j < 4; ++j) {
        int n = n0 + grp * 4 + j;
        obase[(size_t)n * LAT] = acc2[j] + bias;
    }
}

// ---------------------------------------------------------------------------
extern "C" void kernel_launch(void* const* d_in, const int* in_sizes, int n_in,
                              void* d_out, int out_size, void* d_ws, size_t ws_size,
                              hipStream_t stream) {
    const float* x      = (const float*)d_in[0];
    const int*   ei     = (const int*)  d_in[1];
    const float* ea     = (const float*)d_in[2];
    const float* lin_w  = (const float*)d_in[3];
    const float* lin_b  = (const float*)d_in[4];
    const float* kw     = (const float*)d_in[5];
    const float* kb     = (const float*)d_in[6];
    const float* root_w = (const float*)d_in[7];
    const float* conv_b = (const float*)d_in[8];
    const float* mu_w   = (const float*)d_in[9];
    const float* mu_b   = (const float*)d_in[10];
    const float* lv_w   = (const float*)d_in[11];
    const float* lv_b   = (const float*)d_in[12];
    float* out = (float*)d_out;

    float* h   = (float*)d_ws;                          // 1,280,000 f32
    float* num = h   + (size_t)N_NODES * HID;           // 1,280,000 f32
    float* cnt = num + (size_t)N_NODES * HID;           // 20,000 f32
    __hip_bfloat16* kwT   = (__hip_bfloat16*)(cnt + N_NODES);  // 65536
    __hip_bfloat16* kbb8  = kwT   + 65536;                     // 32768
    __hip_bfloat16* wT    = kbb8  + 32768;                     // 8192
    __hip_bfloat16* rootT = wT    + 8192;                      // 4096
    __hip_bfloat16* mlvT  = rootT + 4096;                      // 4096

    hipMemsetAsync(num, 0, (size_t)(N_NODES * HID + N_NODES) * sizeof(float),
                   stream);

    k_prep<<<448, 256, 0, stream>>>(kw, kb, lin_w, root_w, mu_w, lv_w,
                                    kwT, kbb8, wT, rootT, mlvT);

    k_lin_mfma<<<N_NODES / 16, 256, 0, stream>>>(x, wT, lin_b, h);

    k_edge<<<N_EDGES / 16, 256, 0, stream>>>(ei, ea, h, kwT, num, cnt);

    k_out<<<N_NODES / 16, 256, 0, stream>>>(h, num, cnt, rootT, conv_b,
                                            mlvT, mu_b, lv_b, out);
}